// Round 2
// baseline (70.247 us; speedup 1.0000x reference)
//
#include <hip/hip_runtime.h>
#include <hip/hip_bf16.h>

#define NPTS  262144
#define UNITS 256
#define TPB   256
#define NBLK  1024   // NBLK * TPB * 1 point == NPTS

#if defined(__has_builtin)
#if __has_builtin(__builtin_amdgcn_exp2f)
#define HAVE_AMD_EXP2 1
#endif
#endif

__device__ __forceinline__ float fexp2(float x) {
#ifdef HAVE_AMD_EXP2
    return __builtin_amdgcn_exp2f(x);
#else
    return exp2f(x);
#endif
}

// coef record per unit j: 16 floats = [A,B,C,D,E,F,w,pad]_u ++ [A,B,C,D,E,F,w,pad]_v
// gneg = A*x + B*y + D*(x^2+y^2) + C   (= -beta*log2e*r2)
// phi  = exp2(gneg)
// lapc = E*gneg + F                    (= 4*beta^2*r2 - 4*beta)
__global__ __launch_bounds__(512) void rbf_prep(
    const float* __restrict__ mu_u, const float* __restrict__ beta_u,
    const float* __restrict__ W_u,
    const float* __restrict__ mu_v, const float* __restrict__ beta_v,
    const float* __restrict__ W_v,
    float* __restrict__ coef)
{
    const int t   = threadIdx.x;
    const int net = t >> 8;      // 0 = u, 1 = v
    const int j   = t & 255;
    const float* mu = net ? mu_v   : mu_u;
    const float* be = net ? beta_v : beta_u;
    const float* W  = net ? W_v    : W_u;
    const float mx = mu[j], my = mu[UNITS + j];
    const float b  = be[j], w  = W[j];
    const float L   = 1.4426950408889634f;
    const float LN2 = 0.6931471805599453f;
    const float bL  = b * L;
    float* r = coef + j * 16 + net * 8;
    r[0] = 2.0f * bL * mx;                    // A
    r[1] = 2.0f * bL * my;                    // B
    r[2] = -bL * (mx * mx + my * my);         // C
    r[3] = -bL;                               // D
    r[4] = -4.0f * b * LN2;                   // E
    r[5] = -4.0f * b;                         // F
    r[6] = w;
    r[7] = 0.0f;
}

__global__ __launch_bounds__(TPB) void rbf_main(
    const float* __restrict__ gx, const float* __restrict__ gy,
    const float* __restrict__ gu, const float* __restrict__ gv,
    const float* __restrict__ gdu, const float* __restrict__ gdv,
    const float* __restrict__ coef,
    const float* __restrict__ p_d, const float* __restrict__ p_a,
    const float* __restrict__ p_b, const float* __restrict__ p_um,
    const float* __restrict__ p_vm, const float* __restrict__ p_us,
    const float* __restrict__ p_vs,
    float* __restrict__ part)
{
    const int tid = threadIdx.x;
    const int bid = blockIdx.x;
    const int i   = bid * TPB + tid;

    const float x = gx[i], y = gy[i];
    const float x2y2 = fmaf(x, x, y * y);

    float up = 0.f, lu = 0.f, vp = 0.f, lv = 0.f;

    #pragma unroll 4
    for (int j = 0; j < UNITS; ++j) {
        const float* r = coef + j * 16;
        {   // net u
            const float g  = fmaf(r[0], x, fmaf(r[1], y, fmaf(r[3], x2y2, r[2])));
            const float ph = fexp2(g);
            const float c  = fmaf(r[4], g, r[5]);
            const float pw = ph * r[6];
            up += pw;
            lu = fmaf(pw, c, lu);
        }
        {   // net v
            const float g  = fmaf(r[8], x, fmaf(r[9], y, fmaf(r[11], x2y2, r[10])));
            const float ph = fexp2(g);
            const float c  = fmaf(r[12], g, r[13]);
            const float pw = ph * r[14];
            vp += pw;
            lv = fmaf(pw, c, lv);
        }
    }

    // ---- residuals ----
    const float d  = p_d[0],  a = p_a[0],  b = p_b[0];
    const float um = p_um[0], vm = p_vm[0];
    const float us = p_us[0], vs = p_vs[0];
    const float iu  = 1.0f / us, iv = 1.0f / vs;
    const float cau = (a - um) * iu;        // a/us - um/us
    const float c4b = 4.0f * b * iu;        // 4b/us
    const float cbv = b * iv;               // b/vs

    const float uu  = gu[i],  vv  = gv[i];
    const float ddu = gdu[i], ddv = gdv[i];

    float s0, s1, s2, s3, s4, s5;
    {
        float eu = up - uu; s0 = eu * eu;
        float ev = vp - vv; s1 = ev * ev;
        float uph = fmaf(up, us, um);
        float vph = fmaf(vp, vs, vm);
        float den = fmaf(uph, uph, 1.0f);
        float uvd = uph * vph / den;
        float rpu = fmaf(d, lu, cau) - up - c4b * uvd;
        s2 = rpu * rpu;
        float rdu = lu - ddu; s3 = rdu * rdu;
        float rpv = fmaf(uph, iv, lv) - cbv * uvd;
        s4 = rpv * rpv;
        float rdv = lv - ddv; s5 = rdv * rdv;
    }

    // ---- block reduction (deterministic) ----
    float s[6] = { s0, s1, s2, s3, s4, s5 };
    __shared__ float red[4][6];
    #pragma unroll
    for (int k = 0; k < 6; ++k) {
        float vsum = s[k];
        for (int off = 32; off > 0; off >>= 1)
            vsum += __shfl_down(vsum, off);
        s[k] = vsum;
    }
    const int lane = tid & 63;
    const int wid  = tid >> 6;
    if (lane == 0) {
        #pragma unroll
        for (int k = 0; k < 6; ++k) red[wid][k] = s[k];
    }
    __syncthreads();
    if (tid < 6) {
        float p = red[0][tid] + red[1][tid] + red[2][tid] + red[3][tid];
        part[tid * NBLK + bid] = p;
    }
}

__global__ __launch_bounds__(256) void rbf_final(
    const float* __restrict__ part, float* __restrict__ out)
{
    const int tid = threadIdx.x;
    __shared__ float red[4][6];
    float s[6];
    #pragma unroll
    for (int k = 0; k < 6; ++k) {
        const float* p = part + k * NBLK;
        float vsum = p[tid] + p[tid + 256] + p[tid + 512] + p[tid + 768];
        for (int off = 32; off > 0; off >>= 1)
            vsum += __shfl_down(vsum, off);
        s[k] = vsum;
    }
    const int lane = tid & 63;
    const int wid  = tid >> 6;
    if (lane == 0) {
        #pragma unroll
        for (int k = 0; k < 6; ++k) red[wid][k] = s[k];
    }
    __syncthreads();
    if (tid == 0) {
        const float inv = 1.0f / (float)NPTS;
        const float Lu  = (red[0][0] + red[1][0] + red[2][0] + red[3][0]) * inv;
        const float Lv  = (red[0][1] + red[1][1] + red[2][1] + red[3][1]) * inv;
        const float Lpu = (red[0][2] + red[1][2] + red[2][2] + red[3][2]) * inv;
        const float Ldu = (red[0][3] + red[1][3] + red[2][3] + red[3][3]) * inv;
        const float Lpv = (red[0][4] + red[1][4] + red[2][4] + red[3][4]) * inv;
        const float Ldv = (red[0][5] + red[1][5] + red[2][5] + red[3][5]) * inv;
        out[0] = 0.1f * Lu + 0.1f * Lv + Lpu + Ldu + Lpv + Ldv;
        out[1] = Lu;
        out[2] = Lpu;
        out[3] = Lv;
        out[4] = Lpv;
        out[5] = Ldu;
        out[6] = Ldv;
    }
}

extern "C" void kernel_launch(void* const* d_in, const int* in_sizes, int n_in,
                              void* d_out, int out_size, void* d_ws, size_t ws_size,
                              hipStream_t stream) {
    const float* gx   = (const float*)d_in[0];
    const float* gy   = (const float*)d_in[1];
    const float* gu   = (const float*)d_in[2];
    const float* gv   = (const float*)d_in[3];
    const float* gdu  = (const float*)d_in[4];
    const float* gdv  = (const float*)d_in[5];
    const float* mu_u = (const float*)d_in[6];
    const float* be_u = (const float*)d_in[7];
    const float* W_u  = (const float*)d_in[8];
    const float* mu_v = (const float*)d_in[9];
    const float* be_v = (const float*)d_in[10];
    const float* W_v  = (const float*)d_in[11];
    const float* p_d  = (const float*)d_in[12];
    const float* p_a  = (const float*)d_in[13];
    const float* p_b  = (const float*)d_in[14];
    const float* p_um = (const float*)d_in[15];
    const float* p_vm = (const float*)d_in[16];
    const float* p_us = (const float*)d_in[17];
    const float* p_vs = (const float*)d_in[18];

    float* coef = (float*)d_ws;                      // 256*16 floats = 16 KB
    float* part = (float*)d_ws + UNITS * 16;         // 6 * NBLK floats = 24 KB
    float* out  = (float*)d_out;                     // 7 floats

    rbf_prep<<<1, 512, 0, stream>>>(mu_u, be_u, W_u, mu_v, be_v, W_v, coef);
    rbf_main<<<NBLK, TPB, 0, stream>>>(gx, gy, gu, gv, gdu, gdv, coef,
                                       p_d, p_a, p_b, p_um, p_vm, p_us, p_vs,
                                       part);
    rbf_final<<<1, 256, 0, stream>>>(part, out);
}

// Round 3
// 50.415 us; speedup vs baseline: 1.3934x; 1.3934x over previous
//
#include <hip/hip_runtime.h>
#include <hip/hip_bf16.h>

#define NPTS  262144
#define UNITS 256
#define TPB   256
#define NBLK  512   // NBLK * TPB * 2 points == NPTS

#if defined(__has_builtin)
#if __has_builtin(__builtin_amdgcn_exp2f)
#define HAVE_AMD_EXP2 1
#endif
#endif

__device__ __forceinline__ float fexp2(float x) {
#ifdef HAVE_AMD_EXP2
    return __builtin_amdgcn_exp2f(x);
#else
    return exp2f(x);
#endif
}

// coef record per unit j (16 floats):
//   [A_u,B_u,C_u,D_u] [E_u,F_u,S_u,0] [A_v,B_v,C_v,D_v] [E_v,F_v,S_v,0]
// g'   = A*x + B*y + D*(x^2+y^2) + C      (= -beta*log2e*r2 + log2|w|)
// ph'  = exp2(g') = |w| * exp(-beta*r2)
// c_s  = E*g' + F                         (= sign(w) * (4*beta^2*r2 - 4*beta))
// pred += ph' * S      (S = sign(w))
// lap  += ph' * c_s
__global__ __launch_bounds__(512) void rbf_prep(
    const float* __restrict__ mu_u, const float* __restrict__ beta_u,
    const float* __restrict__ W_u,
    const float* __restrict__ mu_v, const float* __restrict__ beta_v,
    const float* __restrict__ W_v,
    float* __restrict__ coef)
{
    const int t   = threadIdx.x;
    const int net = t >> 8;      // 0 = u, 1 = v
    const int j   = t & 255;
    const float* mu = net ? mu_v   : mu_u;
    const float* be = net ? beta_v : beta_u;
    const float* W  = net ? W_v    : W_u;
    const float mx = mu[j], my = mu[UNITS + j];
    const float b  = be[j], w  = W[j];
    const float L   = 1.4426950408889634f;
    const float LN2 = 0.6931471805599453f;
    const float bL  = b * L;
    const float lw  = fmaxf(log2f(fabsf(w)), -100.0f);
    const float sg  = (w >= 0.0f) ? 1.0f : -1.0f;
    const float E   = -4.0f * b * LN2;
    const float F   = -4.0f * b;
    float* r = coef + j * 16 + net * 8;
    r[0] = 2.0f * bL * mx;                         // A
    r[1] = 2.0f * bL * my;                         // B
    r[2] = fmaf(-bL, mx * mx + my * my, lw);       // C' = -bL*(mx^2+my^2) + lw
    r[3] = -bL;                                    // D
    r[4] = sg * E;                                 // E'
    r[5] = sg * (F - E * lw);                      // F'''
    r[6] = sg;                                     // S
    r[7] = 0.0f;
}

__global__ __launch_bounds__(TPB) void rbf_main(
    const float* __restrict__ gx, const float* __restrict__ gy,
    const float* __restrict__ gu, const float* __restrict__ gv,
    const float* __restrict__ gdu, const float* __restrict__ gdv,
    const float4* __restrict__ coef4,
    const float* __restrict__ p_d, const float* __restrict__ p_a,
    const float* __restrict__ p_b, const float* __restrict__ p_um,
    const float* __restrict__ p_vm, const float* __restrict__ p_us,
    const float* __restrict__ p_vs,
    float* __restrict__ part)
{
    const int tid = threadIdx.x;
    const int bid = blockIdx.x;
    const int i0  = bid * TPB + tid;
    const int i1  = i0 + NBLK * TPB;

    __shared__ float4 sc[UNITS * 4];   // 16 KB
    #pragma unroll
    for (int k = 0; k < 4; ++k)
        sc[k * TPB + tid] = coef4[k * TPB + tid];
    __syncthreads();

    const float x0 = gx[i0], y0 = gy[i0];
    const float x1 = gx[i1], y1 = gy[i1];
    const float q0 = fmaf(x0, x0, y0 * y0);
    const float q1 = fmaf(x1, x1, y1 * y1);

    float up0 = 0.f, lu0 = 0.f, vp0 = 0.f, lv0 = 0.f;
    float up1 = 0.f, lu1 = 0.f, vp1 = 0.f, lv1 = 0.f;

    #pragma unroll 4
    for (int j = 0; j < UNITS; ++j) {
        const float4 a = sc[j * 4 + 0];   // A_u,B_u,C_u,D_u
        const float4 b = sc[j * 4 + 1];   // E_u,F_u,S_u,-
        const float4 c = sc[j * 4 + 2];   // A_v,B_v,C_v,D_v
        const float4 d = sc[j * 4 + 3];   // E_v,F_v,S_v,-

        {   // net u, point 0
            const float g  = fmaf(a.x, x0, fmaf(a.y, y0, fmaf(a.w, q0, a.z)));
            const float ph = fexp2(g);
            const float cs = fmaf(b.x, g, b.y);
            up0 = fmaf(ph, b.z, up0);
            lu0 = fmaf(ph, cs, lu0);
        }
        {   // net u, point 1
            const float g  = fmaf(a.x, x1, fmaf(a.y, y1, fmaf(a.w, q1, a.z)));
            const float ph = fexp2(g);
            const float cs = fmaf(b.x, g, b.y);
            up1 = fmaf(ph, b.z, up1);
            lu1 = fmaf(ph, cs, lu1);
        }
        {   // net v, point 0
            const float g  = fmaf(c.x, x0, fmaf(c.y, y0, fmaf(c.w, q0, c.z)));
            const float ph = fexp2(g);
            const float cs = fmaf(d.x, g, d.y);
            vp0 = fmaf(ph, d.z, vp0);
            lv0 = fmaf(ph, cs, lv0);
        }
        {   // net v, point 1
            const float g  = fmaf(c.x, x1, fmaf(c.y, y1, fmaf(c.w, q1, c.z)));
            const float ph = fexp2(g);
            const float cs = fmaf(d.x, g, d.y);
            vp1 = fmaf(ph, d.z, vp1);
            lv1 = fmaf(ph, cs, lv1);
        }
    }

    // ---- residuals ----
    const float dd = p_d[0],  aa = p_a[0], bb = p_b[0];
    const float um = p_um[0], vm = p_vm[0];
    const float us = p_us[0], vs = p_vs[0];
    const float iu  = 1.0f / us, iv = 1.0f / vs;
    const float cau = (aa - um) * iu;       // a/us - um/us
    const float c4b = 4.0f * bb * iu;       // 4b/us
    const float cbv = bb * iv;              // b/vs

    float s0 = 0.f, s1 = 0.f, s2 = 0.f, s3 = 0.f, s4 = 0.f, s5 = 0.f;
    {   // point 0
        const float uu = gu[i0], vv = gv[i0];
        const float ddu = gdu[i0], ddv = gdv[i0];
        float eu = up0 - uu; s0 += eu * eu;
        float ev = vp0 - vv; s1 += ev * ev;
        float uph = fmaf(up0, us, um);
        float vph = fmaf(vp0, vs, vm);
        float den = fmaf(uph, uph, 1.0f);
        float uvd = uph * vph / den;
        float rpu = fmaf(dd, lu0, cau) - up0 - c4b * uvd;
        s2 += rpu * rpu;
        float rdu = lu0 - ddu; s3 += rdu * rdu;
        float rpv = fmaf(uph, iv, lv0) - cbv * uvd;
        s4 += rpv * rpv;
        float rdv = lv0 - ddv; s5 += rdv * rdv;
    }
    {   // point 1
        const float uu = gu[i1], vv = gv[i1];
        const float ddu = gdu[i1], ddv = gdv[i1];
        float eu = up1 - uu; s0 += eu * eu;
        float ev = vp1 - vv; s1 += ev * ev;
        float uph = fmaf(up1, us, um);
        float vph = fmaf(vp1, vs, vm);
        float den = fmaf(uph, uph, 1.0f);
        float uvd = uph * vph / den;
        float rpu = fmaf(dd, lu1, cau) - up1 - c4b * uvd;
        s2 += rpu * rpu;
        float rdu = lu1 - ddu; s3 += rdu * rdu;
        float rpv = fmaf(uph, iv, lv1) - cbv * uvd;
        s4 += rpv * rpv;
        float rdv = lv1 - ddv; s5 += rdv * rdv;
    }

    // ---- block reduction (deterministic) ----
    float s[6] = { s0, s1, s2, s3, s4, s5 };
    __shared__ float red[4][6];
    #pragma unroll
    for (int k = 0; k < 6; ++k) {
        float vsum = s[k];
        for (int off = 32; off > 0; off >>= 1)
            vsum += __shfl_down(vsum, off);
        s[k] = vsum;
    }
    const int lane = tid & 63;
    const int wid  = tid >> 6;
    if (lane == 0) {
        #pragma unroll
        for (int k = 0; k < 6; ++k) red[wid][k] = s[k];
    }
    __syncthreads();
    if (tid < 6) {
        float p = red[0][tid] + red[1][tid] + red[2][tid] + red[3][tid];
        part[tid * NBLK + bid] = p;
    }
}

__global__ __launch_bounds__(256) void rbf_final(
    const float* __restrict__ part, float* __restrict__ out)
{
    const int tid = threadIdx.x;
    __shared__ float red[4][6];
    float s[6];
    #pragma unroll
    for (int k = 0; k < 6; ++k) {
        const float* p = part + k * NBLK;
        float vsum = p[tid] + p[tid + 256];
        for (int off = 32; off > 0; off >>= 1)
            vsum += __shfl_down(vsum, off);
        s[k] = vsum;
    }
    const int lane = tid & 63;
    const int wid  = tid >> 6;
    if (lane == 0) {
        #pragma unroll
        for (int k = 0; k < 6; ++k) red[wid][k] = s[k];
    }
    __syncthreads();
    if (tid == 0) {
        const float inv = 1.0f / (float)NPTS;
        const float Lu  = (red[0][0] + red[1][0] + red[2][0] + red[3][0]) * inv;
        const float Lv  = (red[0][1] + red[1][1] + red[2][1] + red[3][1]) * inv;
        const float Lpu = (red[0][2] + red[1][2] + red[2][2] + red[3][2]) * inv;
        const float Ldu = (red[0][3] + red[1][3] + red[2][3] + red[3][3]) * inv;
        const float Lpv = (red[0][4] + red[1][4] + red[2][4] + red[3][4]) * inv;
        const float Ldv = (red[0][5] + red[1][5] + red[2][5] + red[3][5]) * inv;
        out[0] = 0.1f * Lu + 0.1f * Lv + Lpu + Ldu + Lpv + Ldv;
        out[1] = Lu;
        out[2] = Lpu;
        out[3] = Lv;
        out[4] = Lpv;
        out[5] = Ldu;
        out[6] = Ldv;
    }
}

extern "C" void kernel_launch(void* const* d_in, const int* in_sizes, int n_in,
                              void* d_out, int out_size, void* d_ws, size_t ws_size,
                              hipStream_t stream) {
    const float* gx   = (const float*)d_in[0];
    const float* gy   = (const float*)d_in[1];
    const float* gu   = (const float*)d_in[2];
    const float* gv   = (const float*)d_in[3];
    const float* gdu  = (const float*)d_in[4];
    const float* gdv  = (const float*)d_in[5];
    const float* mu_u = (const float*)d_in[6];
    const float* be_u = (const float*)d_in[7];
    const float* W_u  = (const float*)d_in[8];
    const float* mu_v = (const float*)d_in[9];
    const float* be_v = (const float*)d_in[10];
    const float* W_v  = (const float*)d_in[11];
    const float* p_d  = (const float*)d_in[12];
    const float* p_a  = (const float*)d_in[13];
    const float* p_b  = (const float*)d_in[14];
    const float* p_um = (const float*)d_in[15];
    const float* p_vm = (const float*)d_in[16];
    const float* p_us = (const float*)d_in[17];
    const float* p_vs = (const float*)d_in[18];

    float* coef = (float*)d_ws;                      // 256*16 floats = 16 KB
    float* part = (float*)d_ws + UNITS * 16;         // 6 * NBLK floats
    float* out  = (float*)d_out;                     // 7 floats

    rbf_prep<<<1, 512, 0, stream>>>(mu_u, be_u, W_u, mu_v, be_v, W_v, coef);
    rbf_main<<<NBLK, TPB, 0, stream>>>(gx, gy, gu, gv, gdu, gdv,
                                       (const float4*)coef,
                                       p_d, p_a, p_b, p_um, p_vm, p_us, p_vs,
                                       part);
    rbf_final<<<1, 256, 0, stream>>>(part, out);
}

// Round 4
// 43.483 us; speedup vs baseline: 1.6155x; 1.1594x over previous
//
#include <hip/hip_runtime.h>
#include <hip/hip_bf16.h>

#define NPTS  262144
#define UNITS 256
#define TPB   512
#define NBLK  512   // NBLK * TPB * 1 point == NPTS

#if defined(__has_builtin)
#if __has_builtin(__builtin_amdgcn_exp2f)
#define HAVE_AMD_EXP2 1
#endif
#endif

__device__ __forceinline__ float fexp2(float x) {
#ifdef HAVE_AMD_EXP2
    return __builtin_amdgcn_exp2f(x);
#else
    return exp2f(x);
#endif
}

typedef float v2f __attribute__((ext_vector_type(2)));

// d = a*b + c on both packed f32 halves; 'a' forced to an SGPR pair (wave-uniform).
__device__ __forceinline__ v2f pk_fma_s(v2f a, v2f b, v2f c) {
    v2f d;
    asm("v_pk_fma_f32 %0, %1, %2, %3" : "=v"(d) : "s"(a), "v"(b), "v"(c));
    return d;
}
// all-VGPR variant
__device__ __forceinline__ v2f pk_fma_v(v2f a, v2f b, v2f c) {
    v2f d;
    asm("v_pk_fma_f32 %0, %1, %2, %3" : "=v"(d) : "v"(a), "v"(b), "v"(c));
    return d;
}

// Per unit j, paired (u,v):
//   coefA[8j..]: A_u,A_v,B_u,B_v,D_u,D_v,E_u,E_v     (SGPR stream)
//   coefS[2j..]: S_u,S_v                               (SGPR stream)
//   coefCF[4j..]: C_u,C_v,F_u,F_v                      (LDS, VGPR addends)
// g'  = A*x + B*y + D*(x^2+y^2) + C   (= -beta*log2e*r2 + log2|w|)
// ph' = exp2(g') = |w|*exp(-beta*r2)
// cs  = E*g' + F                      (= sign(w)*(4*beta^2*r2 - 4*beta))
// pred += ph' * S ;  lap += ph' * cs
__global__ __launch_bounds__(512) void rbf_prep(
    const float* __restrict__ mu_u, const float* __restrict__ beta_u,
    const float* __restrict__ W_u,
    const float* __restrict__ mu_v, const float* __restrict__ beta_v,
    const float* __restrict__ W_v,
    float* __restrict__ coefA, float* __restrict__ coefS,
    float* __restrict__ coefCF)
{
    const int t   = threadIdx.x;
    const int net = t >> 8;      // 0 = u, 1 = v
    const int j   = t & 255;
    const float* mu = net ? mu_v   : mu_u;
    const float* be = net ? beta_v : beta_u;
    const float* W  = net ? W_v    : W_u;
    const float mx = mu[j], my = mu[UNITS + j];
    const float b  = be[j], w  = W[j];
    const float L   = 1.4426950408889634f;
    const float LN2 = 0.6931471805599453f;
    const float bL  = b * L;
    const float lw  = fmaxf(log2f(fabsf(w)), -100.0f);
    const float sg  = (w >= 0.0f) ? 1.0f : -1.0f;
    const float E   = -4.0f * b * LN2;
    const float F   = -4.0f * b;
    coefA[8 * j + 0 + net] = 2.0f * bL * mx;                 // A
    coefA[8 * j + 2 + net] = 2.0f * bL * my;                 // B
    coefA[8 * j + 4 + net] = -bL;                            // D
    coefA[8 * j + 6 + net] = sg * E;                         // E'
    coefS[2 * j + net]     = sg;                             // S
    coefCF[4 * j + 0 + net] = fmaf(-bL, mx * mx + my * my, lw); // C'
    coefCF[4 * j + 2 + net] = sg * (F - E * lw);             // F'''
}

__global__ __launch_bounds__(TPB) void rbf_main(
    const float* __restrict__ gx, const float* __restrict__ gy,
    const float* __restrict__ gu, const float* __restrict__ gv,
    const float* __restrict__ gdu, const float* __restrict__ gdv,
    const float* __restrict__ coefA, const float* __restrict__ coefS,
    const float4* __restrict__ coefCF,
    const float* __restrict__ p_d, const float* __restrict__ p_a,
    const float* __restrict__ p_b, const float* __restrict__ p_um,
    const float* __restrict__ p_vm, const float* __restrict__ p_us,
    const float* __restrict__ p_vs,
    float* __restrict__ part)
{
    const int tid = threadIdx.x;
    const int bid = blockIdx.x;
    const int i   = bid * TPB + tid;

    __shared__ float4 scf[UNITS];   // 4 KB: C_u,C_v,F_u,F_v per j
    if (tid < UNITS) scf[tid] = coefCF[tid];
    __syncthreads();

    const float x = gx[i], y = gy[i];
    const float q = fmaf(x, x, y * y);
    const v2f xx = { x, x };
    const v2f yy = { y, y };
    const v2f qq = { q, q };

    v2f UP = { 0.f, 0.f };   // (u_pred, v_pred)
    v2f LU = { 0.f, 0.f };   // (lap_u, lap_v)

    #pragma unroll 4
    for (int j = 0; j < UNITS; ++j) {
        const v2f Ap = *(const v2f*)(coefA + 8 * j + 0);
        const v2f Bp = *(const v2f*)(coefA + 8 * j + 2);
        const v2f Dp = *(const v2f*)(coefA + 8 * j + 4);
        const v2f Ep = *(const v2f*)(coefA + 8 * j + 6);
        const v2f Sp = *(const v2f*)(coefS + 2 * j);
        const float4 cf = scf[j];
        v2f Cp; Cp.x = cf.x; Cp.y = cf.y;
        v2f Fp; Fp.x = cf.z; Fp.y = cf.w;

        v2f G = pk_fma_s(Dp, qq, Cp);
        G     = pk_fma_s(Bp, yy, G);
        G     = pk_fma_s(Ap, xx, G);
        v2f PH; PH.x = fexp2(G.x); PH.y = fexp2(G.y);
        const v2f CS = pk_fma_s(Ep, G, Fp);
        UP = pk_fma_s(Sp, PH, UP);
        LU = pk_fma_v(PH, CS, LU);
    }

    const float up = UP.x, vp = UP.y, lu = LU.x, lv = LU.y;

    // ---- residuals ----
    const float dd = p_d[0],  aa = p_a[0], bb = p_b[0];
    const float um = p_um[0], vm = p_vm[0];
    const float us = p_us[0], vs = p_vs[0];
    const float iu  = 1.0f / us, iv = 1.0f / vs;
    const float cau = (aa - um) * iu;       // a/us - um/us
    const float c4b = 4.0f * bb * iu;       // 4b/us
    const float cbv = bb * iv;              // b/vs

    const float uu  = gu[i],  vv  = gv[i];
    const float ddu = gdu[i], ddv = gdv[i];

    float s0, s1, s2, s3, s4, s5;
    {
        float eu = up - uu; s0 = eu * eu;
        float ev = vp - vv; s1 = ev * ev;
        float uph = fmaf(up, us, um);
        float vph = fmaf(vp, vs, vm);
        float den = fmaf(uph, uph, 1.0f);
        float uvd = uph * vph / den;
        float rpu = fmaf(dd, lu, cau) - up - c4b * uvd;
        s2 = rpu * rpu;
        float rdu = lu - ddu; s3 = rdu * rdu;
        float rpv = fmaf(uph, iv, lv) - cbv * uvd;
        s4 = rpv * rpv;
        float rdv = lv - ddv; s5 = rdv * rdv;
    }

    // ---- block reduction (deterministic) ----
    float s[6] = { s0, s1, s2, s3, s4, s5 };
    __shared__ float red[8][6];
    #pragma unroll
    for (int k = 0; k < 6; ++k) {
        float vsum = s[k];
        for (int off = 32; off > 0; off >>= 1)
            vsum += __shfl_down(vsum, off);
        s[k] = vsum;
    }
    const int lane = tid & 63;
    const int wid  = tid >> 6;
    if (lane == 0) {
        #pragma unroll
        for (int k = 0; k < 6; ++k) red[wid][k] = s[k];
    }
    __syncthreads();
    if (tid < 6) {
        float p = 0.f;
        #pragma unroll
        for (int w = 0; w < 8; ++w) p += red[w][tid];
        part[tid * NBLK + bid] = p;
    }
}

__global__ __launch_bounds__(256) void rbf_final(
    const float* __restrict__ part, float* __restrict__ out)
{
    const int tid = threadIdx.x;
    __shared__ float red[4][6];
    float s[6];
    #pragma unroll
    for (int k = 0; k < 6; ++k) {
        const float* p = part + k * NBLK;
        float vsum = p[tid] + p[tid + 256];
        for (int off = 32; off > 0; off >>= 1)
            vsum += __shfl_down(vsum, off);
        s[k] = vsum;
    }
    const int lane = tid & 63;
    const int wid  = tid >> 6;
    if (lane == 0) {
        #pragma unroll
        for (int k = 0; k < 6; ++k) red[wid][k] = s[k];
    }
    __syncthreads();
    if (tid == 0) {
        const float inv = 1.0f / (float)NPTS;
        const float Lu  = (red[0][0] + red[1][0] + red[2][0] + red[3][0]) * inv;
        const float Lv  = (red[0][1] + red[1][1] + red[2][1] + red[3][1]) * inv;
        const float Lpu = (red[0][2] + red[1][2] + red[2][2] + red[3][2]) * inv;
        const float Ldu = (red[0][3] + red[1][3] + red[2][3] + red[3][3]) * inv;
        const float Lpv = (red[0][4] + red[1][4] + red[2][4] + red[3][4]) * inv;
        const float Ldv = (red[0][5] + red[1][5] + red[2][5] + red[3][5]) * inv;
        out[0] = 0.1f * Lu + 0.1f * Lv + Lpu + Ldu + Lpv + Ldv;
        out[1] = Lu;
        out[2] = Lpu;
        out[3] = Lv;
        out[4] = Lpv;
        out[5] = Ldu;
        out[6] = Ldv;
    }
}

extern "C" void kernel_launch(void* const* d_in, const int* in_sizes, int n_in,
                              void* d_out, int out_size, void* d_ws, size_t ws_size,
                              hipStream_t stream) {
    const float* gx   = (const float*)d_in[0];
    const float* gy   = (const float*)d_in[1];
    const float* gu   = (const float*)d_in[2];
    const float* gv   = (const float*)d_in[3];
    const float* gdu  = (const float*)d_in[4];
    const float* gdv  = (const float*)d_in[5];
    const float* mu_u = (const float*)d_in[6];
    const float* be_u = (const float*)d_in[7];
    const float* W_u  = (const float*)d_in[8];
    const float* mu_v = (const float*)d_in[9];
    const float* be_v = (const float*)d_in[10];
    const float* W_v  = (const float*)d_in[11];
    const float* p_d  = (const float*)d_in[12];
    const float* p_a  = (const float*)d_in[13];
    const float* p_b  = (const float*)d_in[14];
    const float* p_um = (const float*)d_in[15];
    const float* p_vm = (const float*)d_in[16];
    const float* p_us = (const float*)d_in[17];
    const float* p_vs = (const float*)d_in[18];

    float* coefA  = (float*)d_ws;                 // 2048 floats (8 KB)
    float* coefCF = coefA + UNITS * 8;            // 1024 floats (4 KB)
    float* coefS  = coefCF + UNITS * 4;           // 512 floats (2 KB)
    float* part   = coefS + UNITS * 2;            // 6 * NBLK floats
    float* out    = (float*)d_out;                // 7 floats

    rbf_prep<<<1, 512, 0, stream>>>(mu_u, be_u, W_u, mu_v, be_v, W_v,
                                    coefA, coefS, coefCF);
    rbf_main<<<NBLK, TPB, 0, stream>>>(gx, gy, gu, gv, gdu, gdv,
                                       coefA, coefS, (const float4*)coefCF,
                                       p_d, p_a, p_b, p_um, p_vm, p_us, p_vs,
                                       part);
    rbf_final<<<1, 256, 0, stream>>>(part, out);
}

// Round 5
// 38.724 us; speedup vs baseline: 1.8141x; 1.1229x over previous
//
#include <hip/hip_runtime.h>
#include <hip/hip_bf16.h>

#define NPTS  262144
#define UNITS 256
#define TPB   512
#define PPB   256            // points per block
#define NBLK  1024           // NBLK * PPB == NPTS ; 2 j-halves per point

#if defined(__has_builtin)
#if __has_builtin(__builtin_amdgcn_exp2f)
#define HAVE_AMD_EXP2 1
#endif
#endif

__device__ __forceinline__ float fexp2(float x) {
#ifdef HAVE_AMD_EXP2
    return __builtin_amdgcn_exp2f(x);
#else
    return exp2f(x);
#endif
}

typedef float v2f __attribute__((ext_vector_type(2)));

// d = a*b + c packed f32; 'a' in SGPR pair (wave-uniform stream).
__device__ __forceinline__ v2f pk_fma_s(v2f a, v2f b, v2f c) {
    v2f d;
    asm("v_pk_fma_f32 %0, %1, %2, %3" : "=v"(d) : "s"(a), "v"(b), "v"(c));
    return d;
}
__device__ __forceinline__ v2f pk_fma_v(v2f a, v2f b, v2f c) {
    v2f d;
    asm("v_pk_fma_f32 %0, %1, %2, %3" : "=v"(d) : "v"(a), "v"(b), "v"(c));
    return d;
}

// coefA[8j..]: A_u,A_v,B_u,B_v,D_u,D_v,E_u,E_v   (s_load stream)
// coefS[2j..]: S_u,S_v                            (s_load stream)
// coefCF[4j..]: C_u,C_v,F_u,F_v                   (LDS -> VGPR addends)
// g'  = A*x + B*y + D*(x^2+y^2) + C  (= -beta*log2e*r2 + log2|w|)
// ph' = exp2(g') = |w|*exp(-beta*r2)
// cs  = E*g' + F                     (= sign(w)*(4*beta^2*r2 - 4*beta))
// pred += ph'*S ;  lap += ph'*cs
__global__ __launch_bounds__(512) void rbf_prep(
    const float* __restrict__ mu_u, const float* __restrict__ beta_u,
    const float* __restrict__ W_u,
    const float* __restrict__ mu_v, const float* __restrict__ beta_v,
    const float* __restrict__ W_v,
    float* __restrict__ coefA, float* __restrict__ coefS,
    float* __restrict__ coefCF)
{
    const int t   = threadIdx.x;
    const int net = t >> 8;      // 0 = u, 1 = v
    const int j   = t & 255;
    const float* mu = net ? mu_v   : mu_u;
    const float* be = net ? beta_v : beta_u;
    const float* W  = net ? W_v    : W_u;
    const float mx = mu[j], my = mu[UNITS + j];
    const float b  = be[j], w  = W[j];
    const float L   = 1.4426950408889634f;
    const float LN2 = 0.6931471805599453f;
    const float bL  = b * L;
    const float lw  = fmaxf(log2f(fabsf(w)), -100.0f);
    const float sg  = (w >= 0.0f) ? 1.0f : -1.0f;
    const float E   = -4.0f * b * LN2;
    const float F   = -4.0f * b;
    coefA[8 * j + 0 + net] = 2.0f * bL * mx;                    // A
    coefA[8 * j + 2 + net] = 2.0f * bL * my;                    // B
    coefA[8 * j + 4 + net] = -bL;                               // D
    coefA[8 * j + 6 + net] = sg * E;                            // E'
    coefS[2 * j + net]     = sg;                                // S
    coefCF[4 * j + 0 + net] = fmaf(-bL, mx * mx + my * my, lw); // C'
    coefCF[4 * j + 2 + net] = sg * (F - E * lw);                // F'''
}

__global__ __launch_bounds__(TPB) void rbf_main(
    const float* __restrict__ gx, const float* __restrict__ gy,
    const float* __restrict__ gu, const float* __restrict__ gv,
    const float* __restrict__ gdu, const float* __restrict__ gdv,
    const float* __restrict__ coefA, const float* __restrict__ coefS,
    const float4* __restrict__ coefCF,
    const float* __restrict__ p_d, const float* __restrict__ p_a,
    const float* __restrict__ p_b, const float* __restrict__ p_um,
    const float* __restrict__ p_vm, const float* __restrict__ p_us,
    const float* __restrict__ p_vs,
    float* __restrict__ part)
{
    const int tid  = threadIdx.x;
    const int bid  = blockIdx.x;
    const int pl   = tid & (PPB - 1);              // point-in-block
    const int half = __builtin_amdgcn_readfirstlane(tid >> 8);  // j-half, SGPR
    const int i    = bid * PPB + pl;

    __shared__ float4 scf[UNITS];   // 4 KB: C_u,C_v,F_u,F_v per j
    __shared__ float4 ex[PPB];      // 4 KB: partial exchange
    if (tid < UNITS) scf[tid] = coefCF[tid];
    __syncthreads();

    const float x = gx[i], y = gy[i];
    const float q = fmaf(x, x, y * y);
    const v2f xx = { x, x };
    const v2f yy = { y, y };
    const v2f qq = { q, q };

    v2f UP = { 0.f, 0.f };   // (u_pred, v_pred) partial
    v2f LU = { 0.f, 0.f };   // (lap_u, lap_v) partial

    const int jbase = half << 7;                   // 0 or 128
    const float* cA = coefA + (jbase << 3);
    const float* cS = coefS + (jbase << 1);

    #pragma unroll 4
    for (int jj = 0; jj < 128; ++jj) {
        const v2f Ap = *(const v2f*)(cA + 8 * jj + 0);
        const v2f Bp = *(const v2f*)(cA + 8 * jj + 2);
        const v2f Dp = *(const v2f*)(cA + 8 * jj + 4);
        const v2f Ep = *(const v2f*)(cA + 8 * jj + 6);
        const v2f Sp = *(const v2f*)(cS + 2 * jj);
        const float4 cf = scf[jbase + jj];
        v2f Cp; Cp.x = cf.x; Cp.y = cf.y;
        v2f Fp; Fp.x = cf.z; Fp.y = cf.w;

        v2f G = pk_fma_s(Dp, qq, Cp);
        G     = pk_fma_s(Bp, yy, G);
        G     = pk_fma_s(Ap, xx, G);
        v2f PH; PH.x = fexp2(G.x); PH.y = fexp2(G.y);
        const v2f CS = pk_fma_s(Ep, G, Fp);
        UP = pk_fma_s(Sp, PH, UP);
        LU = pk_fma_v(PH, CS, LU);
    }

    // ---- combine the two j-halves through LDS ----
    if (half == 1) {
        float4 o; o.x = UP.x; o.y = UP.y; o.z = LU.x; o.w = LU.y;
        ex[pl] = o;
    }
    __syncthreads();

    float s0 = 0.f, s1 = 0.f, s2 = 0.f, s3 = 0.f, s4 = 0.f, s5 = 0.f;
    if (half == 0) {
        const float4 o = ex[pl];
        const float up = UP.x + o.x;
        const float vp = UP.y + o.y;
        const float lu = LU.x + o.z;
        const float lv = LU.y + o.w;

        const float dd = p_d[0],  aa = p_a[0], bb = p_b[0];
        const float um = p_um[0], vm = p_vm[0];
        const float us = p_us[0], vs = p_vs[0];
        const float iu  = 1.0f / us, iv = 1.0f / vs;
        const float cau = (aa - um) * iu;       // a/us - um/us
        const float c4b = 4.0f * bb * iu;       // 4b/us
        const float cbv = bb * iv;              // b/vs

        const float uu  = gu[i],  vv  = gv[i];
        const float ddu = gdu[i], ddv = gdv[i];

        float eu = up - uu; s0 = eu * eu;
        float ev = vp - vv; s1 = ev * ev;
        float uph = fmaf(up, us, um);
        float vph = fmaf(vp, vs, vm);
        float den = fmaf(uph, uph, 1.0f);
        float uvd = uph * vph / den;
        float rpu = fmaf(dd, lu, cau) - up - c4b * uvd;
        s2 = rpu * rpu;
        float rdu = lu - ddu; s3 = rdu * rdu;
        float rpv = fmaf(uph, iv, lv) - cbv * uvd;
        s4 = rpv * rpv;
        float rdv = lv - ddv; s5 = rdv * rdv;
    }

    // ---- block reduction (deterministic, all 8 waves) ----
    float s[6] = { s0, s1, s2, s3, s4, s5 };
    __shared__ float red[8][6];
    #pragma unroll
    for (int k = 0; k < 6; ++k) {
        float vsum = s[k];
        for (int off = 32; off > 0; off >>= 1)
            vsum += __shfl_down(vsum, off);
        s[k] = vsum;
    }
    const int lane = tid & 63;
    const int wid  = tid >> 6;
    if (lane == 0) {
        #pragma unroll
        for (int k = 0; k < 6; ++k) red[wid][k] = s[k];
    }
    __syncthreads();
    if (tid < 6) {
        float p = 0.f;
        #pragma unroll
        for (int w = 0; w < 8; ++w) p += red[w][tid];
        part[tid * NBLK + bid] = p;
    }
}

__global__ __launch_bounds__(256) void rbf_final(
    const float* __restrict__ part, float* __restrict__ out)
{
    const int tid = threadIdx.x;
    __shared__ float red[4][6];
    float s[6];
    #pragma unroll
    for (int k = 0; k < 6; ++k) {
        const float* p = part + k * NBLK;
        float vsum = p[tid] + p[tid + 256] + p[tid + 512] + p[tid + 768];
        for (int off = 32; off > 0; off >>= 1)
            vsum += __shfl_down(vsum, off);
        s[k] = vsum;
    }
    const int lane = tid & 63;
    const int wid  = tid >> 6;
    if (lane == 0) {
        #pragma unroll
        for (int k = 0; k < 6; ++k) red[wid][k] = s[k];
    }
    __syncthreads();
    if (tid == 0) {
        const float inv = 1.0f / (float)NPTS;
        const float Lu  = (red[0][0] + red[1][0] + red[2][0] + red[3][0]) * inv;
        const float Lv  = (red[0][1] + red[1][1] + red[2][1] + red[3][1]) * inv;
        const float Lpu = (red[0][2] + red[1][2] + red[2][2] + red[3][2]) * inv;
        const float Ldu = (red[0][3] + red[1][3] + red[2][3] + red[3][3]) * inv;
        const float Lpv = (red[0][4] + red[1][4] + red[2][4] + red[3][4]) * inv;
        const float Ldv = (red[0][5] + red[1][5] + red[2][5] + red[3][5]) * inv;
        out[0] = 0.1f * Lu + 0.1f * Lv + Lpu + Ldu + Lpv + Ldv;
        out[1] = Lu;
        out[2] = Lpu;
        out[3] = Lv;
        out[4] = Lpv;
        out[5] = Ldu;
        out[6] = Ldv;
    }
}

extern "C" void kernel_launch(void* const* d_in, const int* in_sizes, int n_in,
                              void* d_out, int out_size, void* d_ws, size_t ws_size,
                              hipStream_t stream) {
    const float* gx   = (const float*)d_in[0];
    const float* gy   = (const float*)d_in[1];
    const float* gu   = (const float*)d_in[2];
    const float* gv   = (const float*)d_in[3];
    const float* gdu  = (const float*)d_in[4];
    const float* gdv  = (const float*)d_in[5];
    const float* mu_u = (const float*)d_in[6];
    const float* be_u = (const float*)d_in[7];
    const float* W_u  = (const float*)d_in[8];
    const float* mu_v = (const float*)d_in[9];
    const float* be_v = (const float*)d_in[10];
    const float* W_v  = (const float*)d_in[11];
    const float* p_d  = (const float*)d_in[12];
    const float* p_a  = (const float*)d_in[13];
    const float* p_b  = (const float*)d_in[14];
    const float* p_um = (const float*)d_in[15];
    const float* p_vm = (const float*)d_in[16];
    const float* p_us = (const float*)d_in[17];
    const float* p_vs = (const float*)d_in[18];

    float* coefA  = (float*)d_ws;                 // 2048 floats (8 KB)
    float* coefCF = coefA + UNITS * 8;            // 1024 floats (4 KB)
    float* coefS  = coefCF + UNITS * 4;           // 512 floats (2 KB)
    float* part   = coefS + UNITS * 2;            // 6 * NBLK floats
    float* out    = (float*)d_out;                // 7 floats

    rbf_prep<<<1, 512, 0, stream>>>(mu_u, be_u, W_u, mu_v, be_v, W_v,
                                    coefA, coefS, coefCF);
    rbf_main<<<NBLK, TPB, 0, stream>>>(gx, gy, gu, gv, gdu, gdv,
                                       coefA, coefS, (const float4*)coefCF,
                                       p_d, p_a, p_b, p_um, p_vm, p_us, p_vs,
                                       part);
    rbf_final<<<1, 256, 0, stream>>>(part, out);
}

// Round 6
// 38.573 us; speedup vs baseline: 1.8212x; 1.0039x over previous
//
#include <hip/hip_runtime.h>
#include <hip/hip_bf16.h>
#include <math.h>

#define NPTS   262144
#define UNITS  256
#define DEG    18          // max total degree (lap polys)
#define STR    19          // rectangular row stride
#define NCO    361         // 19*19 slots per poly
#define NPOLY  4           // Pu, Lu, Pv, Lv
#define CFTOT  (NPOLY*NCO) // 1444
#define P1BLK  128         // prep1 blocks (4 waves each -> 512 (j,net) tasks)
#define MBLK   1024        // main blocks
#define MTPB   256

// ---------------------------------------------------------------------------
// prep1: one wave per (unit j, net). Builds the unit's contribution to the
// global bivariate polynomials in centered coords X=x-0.5, Y=y-0.5:
//   t(X,Y) = beta*((X-ax)^2 + (Y-ay)^2)      (quadratic)
//   w*exp(-t)          ~ sum_m cP[m] * t^m   (deg-8 poly, Taylor@1)
//   w*phi*(4b^2r2-4b)  = 4wb*(t-1)*exp(-t) ~ sum_m cL[m] * t^m  (deg 9)
// Powers t^m are built by repeated in-LDS multiply by the quadratic,
// coefficients distributed 6-per-lane over the 361 rect slots.
// ---------------------------------------------------------------------------
__global__ __launch_bounds__(256) void rbf_prep1(
    const float* __restrict__ mu_u, const float* __restrict__ beta_u,
    const float* __restrict__ W_u,
    const float* __restrict__ mu_v, const float* __restrict__ beta_v,
    const float* __restrict__ W_v,
    float* __restrict__ partial,   // [P1BLK][CFTOT]
    int* __restrict__ flagBlk)     // [P1BLK]
{
    const int tid  = threadIdx.x;
    const int bid  = blockIdx.x;
    const int w    = tid >> 6;          // wave 0..3
    const int lane = tid & 63;
    const int id   = bid * 4 + w;       // 0..511
    const int j    = id >> 1;
    const int net  = id & 1;

    __shared__ float pwA[4][NCO];
    __shared__ float pwB[4][NCO];
    __shared__ int   sflag[4];

    const float* mu = net ? mu_v   : mu_u;
    const float* be = net ? beta_v : beta_u;
    const float* W  = net ? W_v    : W_u;
    const float mx  = mu[j], my = mu[UNITS + j];
    const float b   = be[j], wgt = W[j];

    // validity of the deg-8 approx over safety box [-0.05,1.05]^2: need t-range
    // within [-0.2, 2.2] (|t-1| <= 1.2 -> poly error <= 5.2e-6)
    const float xlo = -0.05f, xhi = 1.05f;
    const float dxl = xlo - mx, dxh = xhi - mx;
    const float dyl = xlo - my, dyh = xhi - my;
    const float dx2max = fmaxf(dxl*dxl, dxh*dxh);
    const float dy2max = fmaxf(dyl*dyl, dyh*dyh);
    const float dx2min = (dxl <= 0.f && dxh >= 0.f) ? 0.f : fminf(dxl*dxl, dxh*dxh);
    const float dy2min = (dyl <= 0.f && dyh >= 0.f) ? 0.f : fminf(dyl*dyl, dyh*dyh);
    const float t1 = b * (dx2min + dy2min);
    const float t2 = b * (dx2max + dy2max);
    const float tlo = fminf(t1, t2), thi = fmaxf(t1, t2);
    const int bad = !(thi <= 2.2f && tlo >= -0.2f);
    if (lane == 0) sflag[w] = bad;

    // quadratic t(X,Y)
    const float ax = mx - 0.5f, ay = my - 0.5f;
    const float qXX = b, qYY = b;
    const float qX = -2.f*b*ax, qY = -2.f*b*ay;
    const float q0 = b*(ax*ax + ay*ay);

    // monomial coeffs of deg-8 Taylor@1 of e^-t (b_i include the e^-1 factor)
    const float bb[10] = { 0.9999988846f, -0.9999897571f, 0.4999582306f,
                           -0.1665676867f, 0.0415142033f, -0.0081750986f,
                           0.0012773592f, -0.000145983906f, 9.12498118e-06f, 0.f };
    const float fourwb = 4.f * wgt * b;
    float cP[10], cL[10];
    #pragma unroll
    for (int m = 0; m < 10; ++m) {
        cP[m] = wgt * bb[m];
        cL[m] = fourwb * ((m ? bb[m-1] : 0.f) - bb[m]);
    }

    // lane-owned slots c = lane + 64r
    int   cidx[6], gi[6], gm[6];
    float accP[6], accL[6];
    #pragma unroll
    for (int r = 0; r < 6; ++r) {
        const int c = lane + 64*r;
        cidx[r] = c;
        const int ii = c / STR;
        gi[r] = ii;
        gm[r] = c - STR*ii;
        accP[r] = (c == 0) ? cP[0] : 0.f;
        accL[r] = (c == 0) ? cL[0] : 0.f;
        float v = 0.f;
        if (c == 0)     v = q0;
        if (c == 1)     v = qY;
        if (c == 2)     v = qYY;
        if (c == STR)   v = qX;
        if (c == 2*STR) v = qXX;
        if (c < NCO) { pwA[w][c] = v; pwB[w][c] = 0.f; }
    }
    __threadfence_block();

    float* A = &pwA[w][0];
    float* B = &pwB[w][0];
    #pragma unroll
    for (int m = 1; m <= 9; ++m) {
        #pragma unroll
        for (int r = 0; r < 6; ++r) {
            if (cidx[r] < NCO) {
                const float p = A[cidx[r]];
                accP[r] = fmaf(cP[m], p, accP[r]);
                accL[r] = fmaf(cL[m], p, accL[r]);
            }
        }
        if (m < 9) {
            #pragma unroll
            for (int r = 0; r < 6; ++r) {
                const int c = cidx[r];
                if (c < NCO) {
                    float acc = q0 * A[c];
                    if (gm[r] >= 1) acc = fmaf(qY,  A[c-1],     acc);
                    if (gm[r] >= 2) acc = fmaf(qYY, A[c-2],     acc);
                    if (gi[r] >= 1) acc = fmaf(qX,  A[c-STR],   acc);
                    if (gi[r] >= 2) acc = fmaf(qXX, A[c-2*STR], acc);
                    B[c] = acc;
                }
            }
            float* T = A; A = B; B = T;
            __threadfence_block();
        }
    }

    // stage per-wave results and fold 4 waves -> block partial
    __syncthreads();
    #pragma unroll
    for (int r = 0; r < 6; ++r) {
        const int c = cidx[r];
        if (c < NCO) { pwA[w][c] = accP[r]; pwB[w][c] = accL[r]; }
    }
    __syncthreads();
    if (tid < NCO) {
        float* dst = partial + bid * CFTOT;
        dst[0*NCO + tid] = pwA[0][tid] + pwA[2][tid];   // Pu
        dst[1*NCO + tid] = pwB[0][tid] + pwB[2][tid];   // Lu
        dst[2*NCO + tid] = pwA[1][tid] + pwA[3][tid];   // Pv
        dst[3*NCO + tid] = pwB[1][tid] + pwB[3][tid];   // Lv
    }
    if (tid == 0)
        flagBlk[bid] = sflag[0] | sflag[1] | sflag[2] | sflag[3];
}

// ---------------------------------------------------------------------------
// prep2: fold 128 block-partials into the final coefficient table + flag.
// ---------------------------------------------------------------------------
__global__ __launch_bounds__(256) void rbf_prep2(
    const float* __restrict__ partial, const int* __restrict__ flagBlk,
    float* __restrict__ coefF, int* __restrict__ flagAll)
{
    const int c = blockIdx.x * 256 + threadIdx.x;
    if (c < CFTOT) {
        float s = 0.f;
        #pragma unroll 8
        for (int p = 0; p < P1BLK; ++p)
            s += partial[p * CFTOT + c];
        coefF[c] = s;
    }
    if (c == CFTOT) {
        int f = 0;
        for (int p = 0; p < P1BLK; ++p) f |= flagBlk[p];
        *flagAll = f;
    }
}

// Horner eval of a (rect-stored, stride 19) bivariate poly of total degree D.
template<int D>
__device__ __forceinline__ float eval_poly(const float* __restrict__ C,
                                           float X, float Y)
{
    float h = 0.f;
    #pragma unroll
    for (int ii = 0; ii <= D; ++ii) {
        const int i = D - ii;
        float r = C[i*STR + (D-i)];
        #pragma unroll
        for (int m = D-i-1; m >= 0; --m)
            r = fmaf(r, Y, C[i*STR + m]);
        h = fmaf(h, X, r);
    }
    return h;
}

__global__ __launch_bounds__(MTPB) void rbf_main(
    const float* __restrict__ gx, const float* __restrict__ gy,
    const float* __restrict__ gu, const float* __restrict__ gv,
    const float* __restrict__ gdu, const float* __restrict__ gdv,
    const float* __restrict__ coefF, const int* __restrict__ flagAll,
    const float* __restrict__ mu_u, const float* __restrict__ beta_u,
    const float* __restrict__ W_u,
    const float* __restrict__ mu_v, const float* __restrict__ beta_v,
    const float* __restrict__ W_v,
    const float* __restrict__ p_d, const float* __restrict__ p_a,
    const float* __restrict__ p_b, const float* __restrict__ p_um,
    const float* __restrict__ p_vm, const float* __restrict__ p_us,
    const float* __restrict__ p_vs,
    float* __restrict__ part)
{
    const int tid = threadIdx.x;
    const int bid = blockIdx.x;
    const int i   = bid * MTPB + tid;

    const float x = gx[i], y = gy[i];
    const int bad = *flagAll;
    const bool inBox = (x >= -0.05f) && (x <= 1.05f) &&
                       (y >= -0.05f) && (y <= 1.05f);

    float up, vp, lu, lv;
    if (!bad && inBox) {
        const float X = x - 0.5f, Y = y - 0.5f;
        up = eval_poly<16>(coefF + 0*NCO, X, Y);
        lu = eval_poly<18>(coefF + 1*NCO, X, Y);
        vp = eval_poly<16>(coefF + 2*NCO, X, Y);
        lv = eval_poly<18>(coefF + 3*NCO, X, Y);
    } else {
        // exact fallback (never taken for in-distribution inputs)
        up = lu = vp = lv = 0.f;
        for (int jj = 0; jj < UNITS; ++jj) {
            {
                const float dx = x - mu_u[jj], dy = y - mu_u[UNITS + jj];
                const float bb_ = beta_u[jj], ww = W_u[jj];
                const float r2 = fmaf(dx, dx, dy * dy);
                const float ph = expf(-bb_ * r2);
                up = fmaf(ww, ph, up);
                lu = fmaf(ww * ph, fmaf(4.f*bb_*bb_, r2, -4.f*bb_), lu);
            }
            {
                const float dx = x - mu_v[jj], dy = y - mu_v[UNITS + jj];
                const float bb_ = beta_v[jj], ww = W_v[jj];
                const float r2 = fmaf(dx, dx, dy * dy);
                const float ph = expf(-bb_ * r2);
                vp = fmaf(ww, ph, vp);
                lv = fmaf(ww * ph, fmaf(4.f*bb_*bb_, r2, -4.f*bb_), lv);
            }
        }
    }

    // ---- residuals ----
    const float dd = p_d[0],  aa = p_a[0], bb = p_b[0];
    const float um = p_um[0], vm = p_vm[0];
    const float us = p_us[0], vs = p_vs[0];
    const float iu  = 1.0f / us, iv = 1.0f / vs;
    const float cau = (aa - um) * iu;
    const float c4b = 4.0f * bb * iu;
    const float cbv = bb * iv;

    const float uu  = gu[i],  vv  = gv[i];
    const float ddu = gdu[i], ddv = gdv[i];

    float s0, s1, s2, s3, s4, s5;
    {
        float eu = up - uu; s0 = eu * eu;
        float ev = vp - vv; s1 = ev * ev;
        float uph = fmaf(up, us, um);
        float vph = fmaf(vp, vs, vm);
        float den = fmaf(uph, uph, 1.0f);
        float uvd = uph * vph / den;
        float rpu = fmaf(dd, lu, cau) - up - c4b * uvd;
        s2 = rpu * rpu;
        float rdu = lu - ddu; s3 = rdu * rdu;
        float rpv = fmaf(uph, iv, lv) - cbv * uvd;
        s4 = rpv * rpv;
        float rdv = lv - ddv; s5 = rdv * rdv;
    }

    // ---- block reduction (deterministic) ----
    float s[6] = { s0, s1, s2, s3, s4, s5 };
    __shared__ float red[4][6];
    #pragma unroll
    for (int k = 0; k < 6; ++k) {
        float vsum = s[k];
        for (int off = 32; off > 0; off >>= 1)
            vsum += __shfl_down(vsum, off);
        s[k] = vsum;
    }
    const int lane = tid & 63;
    const int wid  = tid >> 6;
    if (lane == 0) {
        #pragma unroll
        for (int k = 0; k < 6; ++k) red[wid][k] = s[k];
    }
    __syncthreads();
    if (tid < 6) {
        float p = red[0][tid] + red[1][tid] + red[2][tid] + red[3][tid];
        part[tid * MBLK + bid] = p;
    }
}

__global__ __launch_bounds__(256) void rbf_final(
    const float* __restrict__ part, float* __restrict__ out)
{
    const int tid = threadIdx.x;
    __shared__ float red[4][6];
    float s[6];
    #pragma unroll
    for (int k = 0; k < 6; ++k) {
        const float* p = part + k * MBLK;
        float vsum = p[tid] + p[tid + 256] + p[tid + 512] + p[tid + 768];
        for (int off = 32; off > 0; off >>= 1)
            vsum += __shfl_down(vsum, off);
        s[k] = vsum;
    }
    const int lane = tid & 63;
    const int wid  = tid >> 6;
    if (lane == 0) {
        #pragma unroll
        for (int k = 0; k < 6; ++k) red[wid][k] = s[k];
    }
    __syncthreads();
    if (tid == 0) {
        const float inv = 1.0f / (float)NPTS;
        const float Lu  = (red[0][0] + red[1][0] + red[2][0] + red[3][0]) * inv;
        const float Lv  = (red[0][1] + red[1][1] + red[2][1] + red[3][1]) * inv;
        const float Lpu = (red[0][2] + red[1][2] + red[2][2] + red[3][2]) * inv;
        const float Ldu = (red[0][3] + red[1][3] + red[2][3] + red[3][3]) * inv;
        const float Lpv = (red[0][4] + red[1][4] + red[2][4] + red[3][4]) * inv;
        const float Ldv = (red[0][5] + red[1][5] + red[2][5] + red[3][5]) * inv;
        out[0] = 0.1f * Lu + 0.1f * Lv + Lpu + Ldu + Lpv + Ldv;
        out[1] = Lu;
        out[2] = Lpu;
        out[3] = Lv;
        out[4] = Lpv;
        out[5] = Ldu;
        out[6] = Ldv;
    }
}

extern "C" void kernel_launch(void* const* d_in, const int* in_sizes, int n_in,
                              void* d_out, int out_size, void* d_ws, size_t ws_size,
                              hipStream_t stream) {
    const float* gx   = (const float*)d_in[0];
    const float* gy   = (const float*)d_in[1];
    const float* gu   = (const float*)d_in[2];
    const float* gv   = (const float*)d_in[3];
    const float* gdu  = (const float*)d_in[4];
    const float* gdv  = (const float*)d_in[5];
    const float* mu_u = (const float*)d_in[6];
    const float* be_u = (const float*)d_in[7];
    const float* W_u  = (const float*)d_in[8];
    const float* mu_v = (const float*)d_in[9];
    const float* be_v = (const float*)d_in[10];
    const float* W_v  = (const float*)d_in[11];
    const float* p_d  = (const float*)d_in[12];
    const float* p_a  = (const float*)d_in[13];
    const float* p_b  = (const float*)d_in[14];
    const float* p_um = (const float*)d_in[15];
    const float* p_vm = (const float*)d_in[16];
    const float* p_us = (const float*)d_in[17];
    const float* p_vs = (const float*)d_in[18];

    float* wsf     = (float*)d_ws;
    float* partial = wsf;                        // 128*1444 = 184832 floats
    float* coefF   = wsf + 184832;               // 1444 floats
    float* part    = wsf + 186280;               // 6*1024 floats
    int*   flagBlk = (int*)(wsf + 192448);       // 128 ints
    int*   flagAll = (int*)(wsf + 192584);       // 1 int
    float* out     = (float*)d_out;              // 7 floats

    rbf_prep1<<<P1BLK, 256, 0, stream>>>(mu_u, be_u, W_u, mu_v, be_v, W_v,
                                         partial, flagBlk);
    rbf_prep2<<<6, 256, 0, stream>>>(partial, flagBlk, coefF, flagAll);
    rbf_main<<<MBLK, MTPB, 0, stream>>>(gx, gy, gu, gv, gdu, gdv,
                                        coefF, flagAll,
                                        mu_u, be_u, W_u, mu_v, be_v, W_v,
                                        p_d, p_a, p_b, p_um, p_vm, p_us, p_vs,
                                        part);
    rbf_final<<<1, 256, 0, stream>>>(part, out);
}

// Round 7
// 37.609 us; speedup vs baseline: 1.8678x; 1.0256x over previous
//
#include <hip/hip_runtime.h>
#include <hip/hip_bf16.h>
#include <math.h>

#define NPTS   262144
#define UNITS  256
#define DEG    18          // max total degree (lap polys)
#define STR    19          // rectangular row stride
#define NCO    361         // 19*19 slots per poly
#define NPOLY  4           // Pu, Lu, Pv, Lv
#define CFTOT  (NPOLY*NCO) // 1444
#define P1BLK  128         // prep1 blocks (4 waves each -> 512 (j,net) tasks)
#define MBLK   1024        // main blocks
#define MTPB   256

// ---------------------------------------------------------------------------
// prep1: one wave per (unit j, net). Builds the unit's contribution to the
// global bivariate polynomials in centered coords X=x-0.5, Y=y-0.5:
//   t(X,Y) = beta*((X-ax)^2 + (Y-ay)^2)      (quadratic)
//   w*exp(-t)          ~ sum_m cP[m] * t^m   (deg-8 poly, Taylor@1)
//   w*phi*(4b^2r2-4b)  = 4wb*(t-1)*exp(-t) ~ sum_m cL[m] * t^m  (deg 9)
// ---------------------------------------------------------------------------
__global__ __launch_bounds__(256) void rbf_prep1(
    const float* __restrict__ mu_u, const float* __restrict__ beta_u,
    const float* __restrict__ W_u,
    const float* __restrict__ mu_v, const float* __restrict__ beta_v,
    const float* __restrict__ W_v,
    float* __restrict__ partial,   // [P1BLK][CFTOT]
    int* __restrict__ flagBlk)     // [P1BLK]
{
    const int tid  = threadIdx.x;
    const int bid  = blockIdx.x;
    const int w    = tid >> 6;          // wave 0..3
    const int lane = tid & 63;
    const int id   = bid * 4 + w;       // 0..511
    const int j    = id >> 1;
    const int net  = id & 1;

    __shared__ float pwA[4][NCO];
    __shared__ float pwB[4][NCO];
    __shared__ int   sflag[4];

    const float* mu = net ? mu_v   : mu_u;
    const float* be = net ? beta_v : beta_u;
    const float* W  = net ? W_v    : W_u;
    const float mx  = mu[j], my = mu[UNITS + j];
    const float b   = be[j], wgt = W[j];

    // validity of deg-8 approx over safety box [-0.05,1.05]^2
    const float xlo = -0.05f, xhi = 1.05f;
    const float dxl = xlo - mx, dxh = xhi - mx;
    const float dyl = xlo - my, dyh = xhi - my;
    const float dx2max = fmaxf(dxl*dxl, dxh*dxh);
    const float dy2max = fmaxf(dyl*dyl, dyh*dyh);
    const float dx2min = (dxl <= 0.f && dxh >= 0.f) ? 0.f : fminf(dxl*dxl, dxh*dxh);
    const float dy2min = (dyl <= 0.f && dyh >= 0.f) ? 0.f : fminf(dyl*dyl, dyh*dyh);
    const float t1 = b * (dx2min + dy2min);
    const float t2 = b * (dx2max + dy2max);
    const float tlo = fminf(t1, t2), thi = fmaxf(t1, t2);
    const int bad = !(thi <= 2.2f && tlo >= -0.2f);
    if (lane == 0) sflag[w] = bad;

    // quadratic t(X,Y)
    const float ax = mx - 0.5f, ay = my - 0.5f;
    const float qXX = b, qYY = b;
    const float qX = -2.f*b*ax, qY = -2.f*b*ay;
    const float q0 = b*(ax*ax + ay*ay);

    // monomial coeffs of deg-8 Taylor@1 of e^-t
    const float bb[10] = { 0.9999988846f, -0.9999897571f, 0.4999582306f,
                           -0.1665676867f, 0.0415142033f, -0.0081750986f,
                           0.0012773592f, -0.000145983906f, 9.12498118e-06f, 0.f };
    const float fourwb = 4.f * wgt * b;
    float cP[10], cL[10];
    #pragma unroll
    for (int m = 0; m < 10; ++m) {
        cP[m] = wgt * bb[m];
        cL[m] = fourwb * ((m ? bb[m-1] : 0.f) - bb[m]);
    }

    // lane-owned slots c = lane + 64r
    int   cidx[6], gi[6], gm[6];
    float accP[6], accL[6];
    #pragma unroll
    for (int r = 0; r < 6; ++r) {
        const int c = lane + 64*r;
        cidx[r] = c;
        const int ii = c / STR;
        gi[r] = ii;
        gm[r] = c - STR*ii;
        accP[r] = (c == 0) ? cP[0] : 0.f;
        accL[r] = (c == 0) ? cL[0] : 0.f;
        float v = 0.f;
        if (c == 0)     v = q0;
        if (c == 1)     v = qY;
        if (c == 2)     v = qYY;
        if (c == STR)   v = qX;
        if (c == 2*STR) v = qXX;
        if (c < NCO) { pwA[w][c] = v; pwB[w][c] = 0.f; }
    }
    __threadfence_block();

    float* A = &pwA[w][0];
    float* B = &pwB[w][0];
    #pragma unroll
    for (int m = 1; m <= 9; ++m) {
        #pragma unroll
        for (int r = 0; r < 6; ++r) {
            if (cidx[r] < NCO) {
                const float p = A[cidx[r]];
                accP[r] = fmaf(cP[m], p, accP[r]);
                accL[r] = fmaf(cL[m], p, accL[r]);
            }
        }
        if (m < 9) {
            #pragma unroll
            for (int r = 0; r < 6; ++r) {
                const int c = cidx[r];
                if (c < NCO) {
                    float acc = q0 * A[c];
                    if (gm[r] >= 1) acc = fmaf(qY,  A[c-1],     acc);
                    if (gm[r] >= 2) acc = fmaf(qYY, A[c-2],     acc);
                    if (gi[r] >= 1) acc = fmaf(qX,  A[c-STR],   acc);
                    if (gi[r] >= 2) acc = fmaf(qXX, A[c-2*STR], acc);
                    B[c] = acc;
                }
            }
            float* T = A; A = B; B = T;
            __threadfence_block();
        }
    }

    __syncthreads();
    #pragma unroll
    for (int r = 0; r < 6; ++r) {
        const int c = cidx[r];
        if (c < NCO) { pwA[w][c] = accP[r]; pwB[w][c] = accL[r]; }
    }
    __syncthreads();
    if (tid < NCO) {
        float* dst = partial + bid * CFTOT;
        dst[0*NCO + tid] = pwA[0][tid] + pwA[2][tid];   // Pu
        dst[1*NCO + tid] = pwB[0][tid] + pwB[2][tid];   // Lu
        dst[2*NCO + tid] = pwA[1][tid] + pwA[3][tid];   // Pv
        dst[3*NCO + tid] = pwB[1][tid] + pwB[3][tid];   // Lv
    }
    if (tid == 0)
        flagBlk[bid] = sflag[0] | sflag[1] | sflag[2] | sflag[3];
}

// ---------------------------------------------------------------------------
// prep2: fold 128 block-partials into the final coefficient table + flag.
// ---------------------------------------------------------------------------
__global__ __launch_bounds__(256) void rbf_prep2(
    const float* __restrict__ partial, const int* __restrict__ flagBlk,
    float* __restrict__ coefF, int* __restrict__ flagAll)
{
    const int c = blockIdx.x * 256 + threadIdx.x;
    if (c < CFTOT) {
        float s = 0.f;
        #pragma unroll 8
        for (int p = 0; p < P1BLK; ++p)
            s += partial[p * CFTOT + c];
        coefF[c] = s;
    }
    if (c == CFTOT) {
        int f = 0;
        for (int p = 0; p < P1BLK; ++p) f |= flagBlk[p];
        *flagAll = f;
    }
}

// Horner eval of a (rect-stored, stride 19) bivariate poly of total degree D.
// Called only from wave-uniform control flow -> coefficient loads scalarize.
template<int D>
__device__ __forceinline__ float eval_poly(const float* __restrict__ C,
                                           float X, float Y)
{
    float h = 0.f;
    #pragma unroll
    for (int ii = 0; ii <= D; ++ii) {
        const int i = D - ii;
        float r = C[i*STR + (D-i)];
        #pragma unroll
        for (int m = D-i-1; m >= 0; --m)
            r = fmaf(r, Y, C[i*STR + m]);
        h = fmaf(h, X, r);
    }
    return h;
}

__global__ __launch_bounds__(MTPB) void rbf_main(
    const float* __restrict__ gx, const float* __restrict__ gy,
    const float* __restrict__ gu, const float* __restrict__ gv,
    const float* __restrict__ gdu, const float* __restrict__ gdv,
    const float* __restrict__ coefF, const int* __restrict__ flagAll,
    const float* __restrict__ mu_u, const float* __restrict__ beta_u,
    const float* __restrict__ W_u,
    const float* __restrict__ mu_v, const float* __restrict__ beta_v,
    const float* __restrict__ W_v,
    const float* __restrict__ p_d, const float* __restrict__ p_a,
    const float* __restrict__ p_b, const float* __restrict__ p_um,
    const float* __restrict__ p_vm, const float* __restrict__ p_us,
    const float* __restrict__ p_vs,
    float* __restrict__ part)
{
    const int tid = threadIdx.x;
    const int bid = blockIdx.x;
    const int i   = bid * MTPB + tid;

    const float x = gx[i], y = gy[i];
    // wave-uniform path select: keeps the poly body in uniform control flow
    // so the 686 coefficient loads scalarize to s_load (SGPR broadcast).
    const int bad = __builtin_amdgcn_readfirstlane(*flagAll);
    const bool inBox = (x >= -0.05f) && (x <= 1.05f) &&
                       (y >= -0.05f) && (y <= 1.05f);
    const bool allIn = __all(inBox);

    float up, vp, lu, lv;
    if (!bad && allIn) {
        const float X = x - 0.5f, Y = y - 0.5f;
        up = eval_poly<16>(coefF + 0*NCO, X, Y);
        lu = eval_poly<18>(coefF + 1*NCO, X, Y);
        vp = eval_poly<16>(coefF + 2*NCO, X, Y);
        lv = eval_poly<18>(coefF + 3*NCO, X, Y);
    } else {
        // exact whole-wave fallback (never taken for in-distribution inputs)
        up = lu = vp = lv = 0.f;
        for (int jj = 0; jj < UNITS; ++jj) {
            {
                const float dx = x - mu_u[jj], dy = y - mu_u[UNITS + jj];
                const float bb_ = beta_u[jj], ww = W_u[jj];
                const float r2 = fmaf(dx, dx, dy * dy);
                const float ph = expf(-bb_ * r2);
                up = fmaf(ww, ph, up);
                lu = fmaf(ww * ph, fmaf(4.f*bb_*bb_, r2, -4.f*bb_), lu);
            }
            {
                const float dx = x - mu_v[jj], dy = y - mu_v[UNITS + jj];
                const float bb_ = beta_v[jj], ww = W_v[jj];
                const float r2 = fmaf(dx, dx, dy * dy);
                const float ph = expf(-bb_ * r2);
                vp = fmaf(ww, ph, vp);
                lv = fmaf(ww * ph, fmaf(4.f*bb_*bb_, r2, -4.f*bb_), lv);
            }
        }
    }

    // ---- residuals ----
    const float dd = p_d[0],  aa = p_a[0], bb = p_b[0];
    const float um = p_um[0], vm = p_vm[0];
    const float us = p_us[0], vs = p_vs[0];
    const float iu  = 1.0f / us, iv = 1.0f / vs;
    const float cau = (aa - um) * iu;
    const float c4b = 4.0f * bb * iu;
    const float cbv = bb * iv;

    const float uu  = gu[i],  vv  = gv[i];
    const float ddu = gdu[i], ddv = gdv[i];

    float s0, s1, s2, s3, s4, s5;
    {
        float eu = up - uu; s0 = eu * eu;
        float ev = vp - vv; s1 = ev * ev;
        float uph = fmaf(up, us, um);
        float vph = fmaf(vp, vs, vm);
        float den = fmaf(uph, uph, 1.0f);
        float uvd = uph * vph / den;
        float rpu = fmaf(dd, lu, cau) - up - c4b * uvd;
        s2 = rpu * rpu;
        float rdu = lu - ddu; s3 = rdu * rdu;
        float rpv = fmaf(uph, iv, lv) - cbv * uvd;
        s4 = rpv * rpv;
        float rdv = lv - ddv; s5 = rdv * rdv;
    }

    // ---- block reduction (deterministic) ----
    float s[6] = { s0, s1, s2, s3, s4, s5 };
    __shared__ float red[4][6];
    #pragma unroll
    for (int k = 0; k < 6; ++k) {
        float vsum = s[k];
        for (int off = 32; off > 0; off >>= 1)
            vsum += __shfl_down(vsum, off);
        s[k] = vsum;
    }
    const int lane = tid & 63;
    const int wid  = tid >> 6;
    if (lane == 0) {
        #pragma unroll
        for (int k = 0; k < 6; ++k) red[wid][k] = s[k];
    }
    __syncthreads();
    if (tid < 6) {
        float p = red[0][tid] + red[1][tid] + red[2][tid] + red[3][tid];
        part[tid * MBLK + bid] = p;
    }
}

__global__ __launch_bounds__(256) void rbf_final(
    const float* __restrict__ part, float* __restrict__ out)
{
    const int tid = threadIdx.x;
    __shared__ float red[4][6];
    float s[6];
    #pragma unroll
    for (int k = 0; k < 6; ++k) {
        const float* p = part + k * MBLK;
        float vsum = p[tid] + p[tid + 256] + p[tid + 512] + p[tid + 768];
        for (int off = 32; off > 0; off >>= 1)
            vsum += __shfl_down(vsum, off);
        s[k] = vsum;
    }
    const int lane = tid & 63;
    const int wid  = tid >> 6;
    if (lane == 0) {
        #pragma unroll
        for (int k = 0; k < 6; ++k) red[wid][k] = s[k];
    }
    __syncthreads();
    if (tid == 0) {
        const float inv = 1.0f / (float)NPTS;
        const float Lu  = (red[0][0] + red[1][0] + red[2][0] + red[3][0]) * inv;
        const float Lv  = (red[0][1] + red[1][1] + red[2][1] + red[3][1]) * inv;
        const float Lpu = (red[0][2] + red[1][2] + red[2][2] + red[3][2]) * inv;
        const float Ldu = (red[0][3] + red[1][3] + red[2][3] + red[3][3]) * inv;
        const float Lpv = (red[0][4] + red[1][4] + red[2][4] + red[3][4]) * inv;
        const float Ldv = (red[0][5] + red[1][5] + red[2][5] + red[3][5]) * inv;
        out[0] = 0.1f * Lu + 0.1f * Lv + Lpu + Ldu + Lpv + Ldv;
        out[1] = Lu;
        out[2] = Lpu;
        out[3] = Lv;
        out[4] = Lpv;
        out[5] = Ldu;
        out[6] = Ldv;
    }
}

extern "C" void kernel_launch(void* const* d_in, const int* in_sizes, int n_in,
                              void* d_out, int out_size, void* d_ws, size_t ws_size,
                              hipStream_t stream) {
    const float* gx   = (const float*)d_in[0];
    const float* gy   = (const float*)d_in[1];
    const float* gu   = (const float*)d_in[2];
    const float* gv   = (const float*)d_in[3];
    const float* gdu  = (const float*)d_in[4];
    const float* gdv  = (const float*)d_in[5];
    const float* mu_u = (const float*)d_in[6];
    const float* be_u = (const float*)d_in[7];
    const float* W_u  = (const float*)d_in[8];
    const float* mu_v = (const float*)d_in[9];
    const float* be_v = (const float*)d_in[10];
    const float* W_v  = (const float*)d_in[11];
    const float* p_d  = (const float*)d_in[12];
    const float* p_a  = (const float*)d_in[13];
    const float* p_b  = (const float*)d_in[14];
    const float* p_um = (const float*)d_in[15];
    const float* p_vm = (const float*)d_in[16];
    const float* p_us = (const float*)d_in[17];
    const float* p_vs = (const float*)d_in[18];

    float* wsf     = (float*)d_ws;
    float* partial = wsf;                        // 128*1444 = 184832 floats
    float* coefF   = wsf + 184832;               // 1444 floats
    float* part    = wsf + 186280;               // 6*1024 floats
    int*   flagBlk = (int*)(wsf + 192448);       // 128 ints
    int*   flagAll = (int*)(wsf + 192584);       // 1 int
    float* out     = (float*)d_out;              // 7 floats

    rbf_prep1<<<P1BLK, 256, 0, stream>>>(mu_u, be_u, W_u, mu_v, be_v, W_v,
                                         partial, flagBlk);
    rbf_prep2<<<6, 256, 0, stream>>>(partial, flagBlk, coefF, flagAll);
    rbf_main<<<MBLK, MTPB, 0, stream>>>(gx, gy, gu, gv, gdu, gdv,
                                        coefF, flagAll,
                                        mu_u, be_u, W_u, mu_v, be_v, W_v,
                                        p_d, p_a, p_b, p_um, p_vm, p_us, p_vs,
                                        part);
    rbf_final<<<1, 256, 0, stream>>>(part, out);
}